// Round 1
// baseline (4320.213 us; speedup 1.0000x reference)
//
#include <hip/hip_runtime.h>
#include <hip/hip_bf16.h>
#include <cstdint>
#include <cstddef>

// MMDecoderDoubleBranch: 30-step LSTM decoder + 6 mode heads + confidence head.
// Strategy: per-row independence -> each 64-thread block (1 wave) owns 32 rows
// for all 30 steps. f16 MFMA 16x16x32, fp32 accum/state. Weights prepped into
// B-fragment-friendly f16 layouts in d_ws by prep_weights.

#define HD 128
#define TT 30
#define MM 6
#define KG 160          // gates K: 128 (h) + 16 (x) + 16 (zero pad)
#define B_ROWS 32768

typedef _Float16 f16x8 __attribute__((ext_vector_type(8)));
typedef float f32x4 __attribute__((ext_vector_type(4)));

__device__ __forceinline__ float fast_rcp(float x) { return __builtin_amdgcn_rcpf(x); }
__device__ __forceinline__ float sigm(float x) { return fast_rcp(1.f + __expf(-x)); }
__device__ __forceinline__ float tanhf_(float x) { return 1.f - 2.f * fast_rcp(__expf(2.f * x) + 1.f); }
__device__ __forceinline__ float selu_(float x) {
  const float sc = 1.0507009873554805f;
  const float al = 1.6732632423543772f;
  return x > 0.f ? sc * x : sc * al * (__expf(x) - 1.f);
}

__device__ __forceinline__ f32x4 shx4(f32x4 v, int m) {
  f32x4 r;
  r[0] = __shfl_xor(v[0], m, 64);
  r[1] = __shfl_xor(v[1], m, 64);
  r[2] = __shfl_xor(v[2], m, 64);
  r[3] = __shfl_xor(v[3], m, 64);
  return r;
}

// A(32x128, frags) * B(128x128, prepped row-major-by-output) -> acc[8 col-tiles][2 row-tiles]
__device__ __forceinline__ void gemm128(const f16x8 (&a)[2][4], const _Float16* __restrict__ wp,
                                        int cl, int q, f32x4 (&acc)[8][2]) {
#pragma unroll
  for (int ct = 0; ct < 8; ++ct) {
    const _Float16* bp = wp + (ct * 16 + cl) * HD + q * 8;
    f16x8 b0 = *(const f16x8*)(bp + 0);
    f16x8 b1 = *(const f16x8*)(bp + 32);
    f16x8 b2 = *(const f16x8*)(bp + 64);
    f16x8 b3 = *(const f16x8*)(bp + 96);
    f32x4 a0 = {0.f, 0.f, 0.f, 0.f};
    f32x4 a1 = {0.f, 0.f, 0.f, 0.f};
    a0 = __builtin_amdgcn_mfma_f32_16x16x32_f16(a[0][0], b0, a0, 0, 0, 0);
    a0 = __builtin_amdgcn_mfma_f32_16x16x32_f16(a[0][1], b1, a0, 0, 0, 0);
    a0 = __builtin_amdgcn_mfma_f32_16x16x32_f16(a[0][2], b2, a0, 0, 0, 0);
    a0 = __builtin_amdgcn_mfma_f32_16x16x32_f16(a[0][3], b3, a0, 0, 0, 0);
    a1 = __builtin_amdgcn_mfma_f32_16x16x32_f16(a[1][0], b0, a1, 0, 0, 0);
    a1 = __builtin_amdgcn_mfma_f32_16x16x32_f16(a[1][1], b1, a1, 0, 0, 0);
    a1 = __builtin_amdgcn_mfma_f32_16x16x32_f16(a[1][2], b2, a1, 0, 0, 0);
    a1 = __builtin_amdgcn_mfma_f32_16x16x32_f16(a[1][3], b3, a1, 0, 0, 0);
    acc[ct][0] = a0;
    acc[ct][1] = a1;
  }
}

// Per-row GroupNorm(1 group over 128 ch) stats from C-layout accumulators.
__device__ __forceinline__ void gnstats(const f32x4 (&acc)[8][2], f32x4 (&mean)[2], f32x4 (&rstd)[2]) {
#pragma unroll
  for (int rt = 0; rt < 2; ++rt) {
    f32x4 s1 = {0.f, 0.f, 0.f, 0.f}, s2 = {0.f, 0.f, 0.f, 0.f};
#pragma unroll
    for (int ct = 0; ct < 8; ++ct) { f32x4 v = acc[ct][rt]; s1 += v; s2 += v * v; }
#pragma unroll
    for (int sh = 1; sh < 16; sh <<= 1) { s1 += shx4(s1, sh); s2 += shx4(s2, sh); }
    const f32x4 mu = s1 * (1.f / 128.f);
    const f32x4 va = s2 * (1.f / 128.f) - mu * mu;
    f32x4 rs;
#pragma unroll
    for (int r = 0; r < 4; ++r) rs[r] = rsqrtf(va[r] + 1e-5f);
    mean[rt] = mu;
    rstd[rt] = rs;
  }
}

// ---- weight prep: fp32 inputs -> f16, transposed to "row = output col" layout ----
__global__ __launch_bounds__(256) void prep_weights(
    const float* __restrict__ W_ih, const float* __restrict__ W_hh,
    const float* __restrict__ b_ih, const float* __restrict__ b_hh,
    const float* __restrict__ mW1, const float* __restrict__ mW2,
    const float* __restrict__ cW1, const float* __restrict__ cW2,
    _Float16* __restrict__ Wg, _Float16* __restrict__ W1p, _Float16* __restrict__ W2p,
    _Float16* __restrict__ cW1p, _Float16* __restrict__ cW2p, float* __restrict__ bg) {
  int n = blockIdx.x * 256 + threadIdx.x;
  if (n < 81920) {  // Wg[j][k], j=gate-major output (512), k in [0,160)
    int j = n / KG, k = n % KG;
    float v = 0.f;
    if (k < 128) v = W_hh[j * 128 + k];
    else if (k < 144) v = W_ih[j * 16 + (k - 128)];
    Wg[n] = (_Float16)v;
    return;
  }
  n -= 81920;
  if (n < 98304) {  // W1p[m][e][d] = mW1[m][d][e]
    int m = n >> 14, e = (n >> 7) & 127, d = n & 127;
    W1p[n] = (_Float16)mW1[(m * 128 + d) * 128 + e];
    return;
  }
  n -= 98304;
  if (n < 98304) {  // W2p[m][f][e] = mW2[m][e][f]
    int m = n >> 14, f = (n >> 7) & 127, e = n & 127;
    W2p[n] = (_Float16)mW2[(m * 128 + e) * 128 + f];
    return;
  }
  n -= 98304;
  if (n < 16384) { int f = n >> 7, d = n & 127; cW1p[n] = (_Float16)cW1[d * 128 + f]; return; }
  n -= 16384;
  if (n < 16384) { int f = n >> 7, e = n & 127; cW2p[n] = (_Float16)cW2[e * 128 + f]; return; }
  n -= 16384;
  if (n < 512) bg[n] = b_ih[n] + b_hh[n];
}

// ---- main decoder: 1 wave per block, 32 rows per block, all 30 steps ----
__global__ __launch_bounds__(64, 1) void mmdec_main(
    const float* __restrict__ last_obs_rel, const float* __restrict__ h0, const float* __restrict__ c0,
    const float* __restrict__ W_se, const float* __restrict__ b_se,
    const float* __restrict__ mg1w, const float* __restrict__ mg1b,
    const float* __restrict__ mg2w, const float* __restrict__ mg2b,
    const float* __restrict__ mWo, const float* __restrict__ mbo,
    const float* __restrict__ cg1w, const float* __restrict__ cg1b,
    const float* __restrict__ cg2w, const float* __restrict__ cg2b,
    const float* __restrict__ cWo, const float* __restrict__ cbo,
    const _Float16* __restrict__ Wg, const _Float16* __restrict__ W1p, const _Float16* __restrict__ W2p,
    const _Float16* __restrict__ cW1p, const _Float16* __restrict__ cW2p, const float* __restrict__ bg,
    float* __restrict__ out) {
  // per-row LDS: h rows are [128 h | 16 x | 16 zeros] f16, stride 336 B (16B-aligned, de-pow2'd)
  __shared__ __align__(16) unsigned char h_smem[32 * 336];
  __shared__ __align__(16) unsigned char t1_smem[32 * 272];
  __shared__ __align__(16) float rel_smem[32 * 16];

  const int lane = threadIdx.x;
  const int q = lane >> 4;    // quad: k-offset for A/B frags, row-group for C
  const int cl = lane & 15;   // col within tile (C), row within tile (A), out-col (B)
  const int rowbase = blockIdx.x * 32;

  auto hrow = [&](int r) -> _Float16* { return (_Float16*)(h_smem + r * 336); };
  auto t1row = [&](int r) -> _Float16* { return (_Float16*)(t1_smem + r * 272); };

  // ---- init: h0 -> LDS (f16) ----
  {
    const int rr = lane & 31, half = lane >> 5;
    const float* src = h0 + (size_t)(rowbase + rr) * HD + half * 64;
    _Float16* dst = hrow(rr) + half * 64;
#pragma unroll
    for (int i = 0; i < 64; i += 8) {
      f16x8 v;
#pragma unroll
      for (int k = 0; k < 8; ++k) v[k] = (_Float16)src[i + k];
      *(f16x8*)(dst + i) = v;
    }
  }
  // ---- init: dec_in = selu(tile(last_obs_rel,6) @ W_se.T + b_se) -> LDS x-cols; zero pad ----
  {
    const int rr = lane >> 1, e0 = (lane & 1) * 8;
    const float r0 = last_obs_rel[(size_t)(rowbase + rr) * 2 + 0];
    const float r1 = last_obs_rel[(size_t)(rowbase + rr) * 2 + 1];
    f16x8 v;
#pragma unroll
    for (int i = 0; i < 8; ++i) {
      const int e = e0 + i;
      float acc = b_se[e];
#pragma unroll
      for (int j = 0; j < 12; ++j) acc += ((j & 1) ? r1 : r0) * W_se[e * 12 + j];
      v[i] = (_Float16)selu_(acc);
    }
    *(f16x8*)(hrow(rr) + 128 + e0) = v;
    if (lane < 32) {
      f16x8 z;
#pragma unroll
      for (int i = 0; i < 8; ++i) z[i] = (_Float16)0.f;
      *(f16x8*)(hrow(lane) + 144) = z;
      *(f16x8*)(hrow(lane) + 152) = z;
    }
  }
  // ---- init: c0 -> fp32 registers in MFMA C-layout ----
  f32x4 cacc[2][8];
#pragma unroll
  for (int rt = 0; rt < 2; ++rt)
#pragma unroll
    for (int ct = 0; ct < 8; ++ct)
#pragma unroll
      for (int r = 0; r < 4; ++r)
        cacc[rt][ct][r] = c0[(size_t)(rowbase + rt * 16 + q * 4 + r) * HD + ct * 16 + cl];

  f32x4 hC[2][8];   // new h in C-layout (fp32) for residual adds
  f16x8 ah[2][4];   // A-frags of current h (K=128), reused by all 6 modes (+conf at end)
  __syncthreads();

  const size_t confbase = (size_t)B_ROWS * MM * TT * 2;

  for (int t = 0; t < TT; ++t) {
    // ======== LSTM gates: [h|x|0](K=160) @ Wg^T -> i,f,g,o; update c,h ========
    f16x8 afr[2][5];
#pragma unroll
    for (int rt = 0; rt < 2; ++rt)
#pragma unroll
      for (int ch = 0; ch < 5; ++ch)
        afr[rt][ch] = *(const f16x8*)(hrow(rt * 16 + cl) + ch * 32 + q * 8);

#pragma unroll
    for (int cg = 0; cg < 8; ++cg) {  // 16-channel group; gates i/f/g/o for same channels
      f32x4 gacc[4][2];
#pragma unroll
      for (int g = 0; g < 4; ++g) {
        const _Float16* bp = Wg + (size_t)(g * 128 + cg * 16 + cl) * KG + q * 8;
        f32x4 a0 = {0.f, 0.f, 0.f, 0.f};
        f32x4 a1 = {0.f, 0.f, 0.f, 0.f};
#pragma unroll
        for (int ch = 0; ch < 5; ++ch) {
          f16x8 bfr = *(const f16x8*)(bp + ch * 32);
          a0 = __builtin_amdgcn_mfma_f32_16x16x32_f16(afr[0][ch], bfr, a0, 0, 0, 0);
          a1 = __builtin_amdgcn_mfma_f32_16x16x32_f16(afr[1][ch], bfr, a1, 0, 0, 0);
        }
        gacc[g][0] = a0;
        gacc[g][1] = a1;
      }
      const float bi = bg[cg * 16 + cl];
      const float bf_ = bg[128 + cg * 16 + cl];
      const float bgg = bg[256 + cg * 16 + cl];
      const float bo = bg[384 + cg * 16 + cl];
#pragma unroll
      for (int rt = 0; rt < 2; ++rt) {
        f32x4 hv;
#pragma unroll
        for (int r = 0; r < 4; ++r) {
          const float iv = sigm(gacc[0][rt][r] + bi);
          const float fv = sigm(gacc[1][rt][r] + bf_);
          const float gv = tanhf_(gacc[2][rt][r] + bgg);
          const float ov = sigm(gacc[3][rt][r] + bo);
          const float cn = fv * cacc[rt][cg][r] + iv * gv;
          cacc[rt][cg][r] = cn;
          const float hn = ov * tanhf_(cn);
          hv[r] = hn;
          hrow(rt * 16 + q * 4 + r)[cg * 16 + cl] = (_Float16)hn;  // scatter new h to LDS
        }
        hC[rt][cg] = hv;
      }
    }
    __syncthreads();

    // ======== 6 mode heads ========
#pragma unroll
    for (int rt = 0; rt < 2; ++rt)
#pragma unroll
      for (int ch = 0; ch < 4; ++ch)
        ah[rt][ch] = *(const f16x8*)(hrow(rt * 16 + cl) + ch * 32 + q * 8);

    for (int m = 0; m < MM; ++m) {
      f32x4 tac[8][2];
      gemm128(ah, W1p + (size_t)m * HD * HD, cl, q, tac);
      f32x4 mean[2], rstd[2];
      gnstats(tac, mean, rstd);
#pragma unroll
      for (int ct = 0; ct < 8; ++ct) {  // t1 = relu(gn(.)) -> LDS (f16) for next A-frags
        const float g1 = mg1w[m * HD + ct * 16 + cl];
        const float b1 = mg1b[m * HD + ct * 16 + cl];
#pragma unroll
        for (int rt = 0; rt < 2; ++rt)
#pragma unroll
          for (int r = 0; r < 4; ++r) {
            float v = (tac[ct][rt][r] - mean[rt][r]) * rstd[rt][r] * g1 + b1;
            v = fmaxf(v, 0.f);
            t1row(rt * 16 + q * 4 + r)[ct * 16 + cl] = (_Float16)v;
          }
      }
      __syncthreads();
      f16x8 at1[2][4];
#pragma unroll
      for (int rt = 0; rt < 2; ++rt)
#pragma unroll
        for (int ch = 0; ch < 4; ++ch)
          at1[rt][ch] = *(const f16x8*)(t1row(rt * 16 + cl) + ch * 32 + q * 8);
      f32x4 t2a[8][2];
      gemm128(at1, W2p + (size_t)m * HD * HD, cl, q, t2a);
      gnstats(t2a, mean, rstd);
      // t = relu(gn(t2) + h); out = t @ mWo[m] + mbo[m] (VALU partials + butterfly)
      float po[2][4][2];
#pragma unroll
      for (int rt = 0; rt < 2; ++rt)
#pragma unroll
        for (int r = 0; r < 4; ++r) { po[rt][r][0] = 0.f; po[rt][r][1] = 0.f; }
#pragma unroll
      for (int ct = 0; ct < 8; ++ct) {
        const float g2 = mg2w[m * HD + ct * 16 + cl];
        const float b2 = mg2b[m * HD + ct * 16 + cl];
        const float w0 = mWo[((size_t)m * HD + ct * 16 + cl) * 2 + 0];
        const float w1 = mWo[((size_t)m * HD + ct * 16 + cl) * 2 + 1];
#pragma unroll
        for (int rt = 0; rt < 2; ++rt)
#pragma unroll
          for (int r = 0; r < 4; ++r) {
            float v = (t2a[ct][rt][r] - mean[rt][r]) * rstd[rt][r] * g2 + b2 + hC[rt][ct][r];
            v = fmaxf(v, 0.f);
            po[rt][r][0] += v * w0;
            po[rt][r][1] += v * w1;
          }
      }
#pragma unroll
      for (int sh = 1; sh < 16; sh <<= 1)
#pragma unroll
        for (int rt = 0; rt < 2; ++rt)
#pragma unroll
          for (int r = 0; r < 4; ++r) {
            po[rt][r][0] += __shfl_xor(po[rt][r][0], sh, 64);
            po[rt][r][1] += __shfl_xor(po[rt][r][1], sh, 64);
          }
      if (cl < 2) {  // lanes 0,1 of each quad store o=cl for the quad's 8 rows
#pragma unroll
        for (int rt = 0; rt < 2; ++rt)
#pragma unroll
          for (int r = 0; r < 4; ++r) {
            const int rl_ = rt * 16 + q * 4 + r;
            const float val = (cl ? po[rt][r][1] : po[rt][r][0]) + mbo[m * 2 + cl];
            out[(((size_t)(rowbase + rl_) * MM + m) * TT + t) * 2 + cl] = val;
            rel_smem[rl_ * 16 + m * 2 + cl] = val;
          }
      }
    }
    __syncthreads();

    // ======== xin = selu(rel @ W_se.T + b_se) -> LDS x-cols ========
    {
      const int rr = lane >> 1, e0 = (lane & 1) * 8;
      float rl[12];
#pragma unroll
      for (int j = 0; j < 12; ++j) rl[j] = rel_smem[rr * 16 + j];
      f16x8 v;
#pragma unroll
      for (int i = 0; i < 8; ++i) {
        const int e = e0 + i;
        float acc = b_se[e];
#pragma unroll
        for (int j = 0; j < 12; ++j) acc += rl[j] * W_se[e * 12 + j];
        v[i] = (_Float16)selu_(acc);
      }
      *(f16x8*)(hrow(rr) + 128 + e0) = v;
    }
    __syncthreads();
  }

  // ======== confidence head on hT ========
  {
    f32x4 tac[8][2];
    gemm128(ah, cW1p, cl, q, tac);  // ah still holds hT A-frags
    f32x4 mean[2], rstd[2];
    gnstats(tac, mean, rstd);
#pragma unroll
    for (int ct = 0; ct < 8; ++ct) {
      const float g1 = cg1w[ct * 16 + cl];
      const float b1 = cg1b[ct * 16 + cl];
#pragma unroll
      for (int rt = 0; rt < 2; ++rt)
#pragma unroll
        for (int r = 0; r < 4; ++r) {
          float v = (tac[ct][rt][r] - mean[rt][r]) * rstd[rt][r] * g1 + b1;
          v = fmaxf(v, 0.f);
          t1row(rt * 16 + q * 4 + r)[ct * 16 + cl] = (_Float16)v;
        }
    }
    __syncthreads();
    f16x8 at1[2][4];
#pragma unroll
    for (int rt = 0; rt < 2; ++rt)
#pragma unroll
      for (int ch = 0; ch < 4; ++ch)
        at1[rt][ch] = *(const f16x8*)(t1row(rt * 16 + cl) + ch * 32 + q * 8);
    f32x4 t2a[8][2];
    gemm128(at1, cW2p, cl, q, t2a);
    gnstats(t2a, mean, rstd);

    float pl[2][4][6];
#pragma unroll
    for (int rt = 0; rt < 2; ++rt)
#pragma unroll
      for (int r = 0; r < 4; ++r)
#pragma unroll
        for (int k = 0; k < 6; ++k) pl[rt][r][k] = 0.f;
#pragma unroll
    for (int ct = 0; ct < 8; ++ct) {
      const float g2 = cg2w[ct * 16 + cl];
      const float b2 = cg2b[ct * 16 + cl];
      float wo[6];
#pragma unroll
      for (int k = 0; k < 6; ++k) wo[k] = cWo[(ct * 16 + cl) * 6 + k];
#pragma unroll
      for (int rt = 0; rt < 2; ++rt)
#pragma unroll
        for (int r = 0; r < 4; ++r) {
          float v = (t2a[ct][rt][r] - mean[rt][r]) * rstd[rt][r] * g2 + b2 + hC[rt][ct][r];
          v = fmaxf(v, 0.f);
#pragma unroll
          for (int k = 0; k < 6; ++k) pl[rt][r][k] += v * wo[k];
        }
    }
#pragma unroll
    for (int sh = 1; sh < 16; sh <<= 1)
#pragma unroll
      for (int rt = 0; rt < 2; ++rt)
#pragma unroll
        for (int r = 0; r < 4; ++r)
#pragma unroll
          for (int k = 0; k < 6; ++k) pl[rt][r][k] += __shfl_xor(pl[rt][r][k], sh, 64);
    if (cl == 0) {  // lane 0 of each quad: softmax + store for its 8 rows
#pragma unroll
      for (int rt = 0; rt < 2; ++rt)
#pragma unroll
        for (int r = 0; r < 4; ++r) {
          float l[6];
#pragma unroll
          for (int k = 0; k < 6; ++k) l[k] = pl[rt][r][k] + cbo[k];
          float mx = l[0];
#pragma unroll
          for (int k = 1; k < 6; ++k) mx = fmaxf(mx, l[k]);
          float s = 0.f;
#pragma unroll
          for (int k = 0; k < 6; ++k) { l[k] = __expf(l[k] - mx); s += l[k]; }
          const float inv = fast_rcp(s);
          const size_t row = rowbase + rt * 16 + q * 4 + r;
#pragma unroll
          for (int k = 0; k < 6; ++k) out[confbase + row * 6 + k] = l[k] * inv;
        }
    }
  }
}

extern "C" void kernel_launch(void* const* d_in, const int* in_sizes, int n_in,
                              void* d_out, int out_size, void* d_ws, size_t ws_size,
                              hipStream_t stream) {
  (void)in_sizes; (void)n_in; (void)out_size; (void)ws_size;
  const float* last_obs_rel = (const float*)d_in[1];
  const float* h0   = (const float*)d_in[2];
  const float* c0   = (const float*)d_in[3];
  const float* W_se = (const float*)d_in[4];
  const float* b_se = (const float*)d_in[5];
  const float* W_ih = (const float*)d_in[6];
  const float* W_hh = (const float*)d_in[7];
  const float* b_ih = (const float*)d_in[8];
  const float* b_hh = (const float*)d_in[9];
  const float* mW1  = (const float*)d_in[10];
  const float* mg1w = (const float*)d_in[11];
  const float* mg1b = (const float*)d_in[12];
  const float* mW2  = (const float*)d_in[13];
  const float* mg2w = (const float*)d_in[14];
  const float* mg2b = (const float*)d_in[15];
  const float* mWo  = (const float*)d_in[16];
  const float* mbo  = (const float*)d_in[17];
  const float* cW1  = (const float*)d_in[18];
  const float* cg1w = (const float*)d_in[19];
  const float* cg1b = (const float*)d_in[20];
  const float* cW2  = (const float*)d_in[21];
  const float* cg2w = (const float*)d_in[22];
  const float* cg2b = (const float*)d_in[23];
  const float* cWo  = (const float*)d_in[24];
  const float* cbo  = (const float*)d_in[25];

  char* ws = (char*)d_ws;
  _Float16* Wg   = (_Float16*)(ws + 0);       // 512*160 f16   = 163840 B
  _Float16* W1p  = (_Float16*)(ws + 163840);  // 6*128*128 f16 = 196608 B
  _Float16* W2p  = (_Float16*)(ws + 360448);  // 6*128*128 f16 = 196608 B
  _Float16* cW1p = (_Float16*)(ws + 557056);  // 128*128 f16   =  32768 B
  _Float16* cW2p = (_Float16*)(ws + 589824);  // 128*128 f16   =  32768 B
  float*    bg   = (float*)   (ws + 622592);  // 512 f32       =   2048 B

  prep_weights<<<1218, 256, 0, stream>>>(W_ih, W_hh, b_ih, b_hh, mW1, mW2, cW1, cW2,
                                         Wg, W1p, W2p, cW1p, cW2p, bg);
  mmdec_main<<<1024, 64, 0, stream>>>(last_obs_rel, h0, c0, W_se, b_se,
                                      mg1w, mg1b, mg2w, mg2b, mWo, mbo,
                                      cg1w, cg1b, cg2w, cg2b, cWo, cbo,
                                      Wg, W1p, W2p, cW1p, cW2p, bg, (float*)d_out);
}

// Round 2
// 3956.255 us; speedup vs baseline: 1.0920x; 1.0920x over previous
//
#include <hip/hip_runtime.h>
#include <hip/hip_bf16.h>
#include <cstdint>
#include <cstddef>

// MMDecoderDoubleBranch: 30-step LSTM decoder + 6 mode heads + confidence head.
// Each 64-thread block (1 wave) owns 32 rows for all 30 steps. f16 MFMA
// 16x16x32, fp32 accum/state.
// R2: weights prepped in FRAGMENT ORDER — P[tile][kchunk][lane][8] — so every
// B-fragment load is lane-contiguous (1 KB coalesced per wave instruction).
// R1 had lanes 256 B apart -> 64 cache lines per load -> latency-bound at
// MfmaUtil 5%, FETCH 2.3 GB.

#define HD 128
#define TT 30
#define MM 6
#define KG 160          // gates K: 128 (h) + 16 (x) + 16 (zero pad)
#define B_ROWS 32768

typedef _Float16 f16x8 __attribute__((ext_vector_type(8)));
typedef float f32x4 __attribute__((ext_vector_type(4)));

__device__ __forceinline__ float fast_rcp(float x) { return __builtin_amdgcn_rcpf(x); }
__device__ __forceinline__ float sigm(float x) { return fast_rcp(1.f + __expf(-x)); }
__device__ __forceinline__ float tanhf_(float x) { return 1.f - 2.f * fast_rcp(__expf(2.f * x) + 1.f); }
__device__ __forceinline__ float selu_(float x) {
  const float sc = 1.0507009873554805f;
  const float al = 1.6732632423543772f;
  return x > 0.f ? sc * x : sc * al * (__expf(x) - 1.f);
}

__device__ __forceinline__ f32x4 shx4(f32x4 v, int m) {
  f32x4 r;
  r[0] = __shfl_xor(v[0], m, 64);
  r[1] = __shfl_xor(v[1], m, 64);
  r[2] = __shfl_xor(v[2], m, 64);
  r[3] = __shfl_xor(v[3], m, 64);
  return r;
}

// A(32x128, frags) * B(128x128, fragment-ordered) -> acc[8 ct][2 rt]
// wp layout: [ct][ch][lane][8] f16 -> per-lane offset ct*2048 + ch*512 + lane*8
__device__ __forceinline__ void gemm128(const f16x8 (&a)[2][4], const _Float16* __restrict__ wp,
                                        int lane, f32x4 (&acc)[8][2]) {
#pragma unroll
  for (int ct = 0; ct < 8; ++ct) {
    const _Float16* bp = wp + ct * 2048 + lane * 8;
    f16x8 b0 = *(const f16x8*)(bp + 0);
    f16x8 b1 = *(const f16x8*)(bp + 512);
    f16x8 b2 = *(const f16x8*)(bp + 1024);
    f16x8 b3 = *(const f16x8*)(bp + 1536);
    f32x4 a0 = {0.f, 0.f, 0.f, 0.f};
    f32x4 a1 = {0.f, 0.f, 0.f, 0.f};
    a0 = __builtin_amdgcn_mfma_f32_16x16x32_f16(a[0][0], b0, a0, 0, 0, 0);
    a1 = __builtin_amdgcn_mfma_f32_16x16x32_f16(a[1][0], b0, a1, 0, 0, 0);
    a0 = __builtin_amdgcn_mfma_f32_16x16x32_f16(a[0][1], b1, a0, 0, 0, 0);
    a1 = __builtin_amdgcn_mfma_f32_16x16x32_f16(a[1][1], b1, a1, 0, 0, 0);
    a0 = __builtin_amdgcn_mfma_f32_16x16x32_f16(a[0][2], b2, a0, 0, 0, 0);
    a1 = __builtin_amdgcn_mfma_f32_16x16x32_f16(a[1][2], b2, a1, 0, 0, 0);
    a0 = __builtin_amdgcn_mfma_f32_16x16x32_f16(a[0][3], b3, a0, 0, 0, 0);
    a1 = __builtin_amdgcn_mfma_f32_16x16x32_f16(a[1][3], b3, a1, 0, 0, 0);
    acc[ct][0] = a0;
    acc[ct][1] = a1;
  }
}

// Per-row GroupNorm(1 group over 128 ch) stats from C-layout accumulators.
__device__ __forceinline__ void gnstats(const f32x4 (&acc)[8][2], f32x4 (&mean)[2], f32x4 (&rstd)[2]) {
#pragma unroll
  for (int rt = 0; rt < 2; ++rt) {
    f32x4 s1 = {0.f, 0.f, 0.f, 0.f}, s2 = {0.f, 0.f, 0.f, 0.f};
#pragma unroll
    for (int ct = 0; ct < 8; ++ct) { f32x4 v = acc[ct][rt]; s1 += v; s2 += v * v; }
#pragma unroll
    for (int sh = 1; sh < 16; sh <<= 1) { s1 += shx4(s1, sh); s2 += shx4(s2, sh); }
    const f32x4 mu = s1 * (1.f / 128.f);
    const f32x4 va = s2 * (1.f / 128.f) - mu * mu;
    f32x4 rs;
#pragma unroll
    for (int r = 0; r < 4; ++r) rs[r] = rsqrtf(va[r] + 1e-5f);
    mean[rt] = mu;
    rstd[rt] = rs;
  }
}

// ---- weight prep: fp32 -> f16, fragment-ordered ----
// Wg:   [t16=g*8+cg][ch=0..4][lane][8]   (32 tiles * 2560 = 81920)
// W1p/W2p: per mode [ct][ch=0..3][lane][8] (6 * 16384 = 98304 each)
// cW1p/cW2p: [ct][ch][lane][8] (16384 each)
__global__ __launch_bounds__(256) void prep_weights(
    const float* __restrict__ W_ih, const float* __restrict__ W_hh,
    const float* __restrict__ b_ih, const float* __restrict__ b_hh,
    const float* __restrict__ mW1, const float* __restrict__ mW2,
    const float* __restrict__ cW1, const float* __restrict__ cW2,
    _Float16* __restrict__ Wg, _Float16* __restrict__ W1p, _Float16* __restrict__ W2p,
    _Float16* __restrict__ cW1p, _Float16* __restrict__ cW2p, float* __restrict__ bg) {
  int n = blockIdx.x * 256 + threadIdx.x;
  if (n < 81920) {
    int t16 = n / 2560, r = n % 2560;
    int ch = r / 512, l = (r >> 3) & 63, j = r & 7;
    int q = l >> 4, cl = l & 15;
    int row = (t16 >> 3) * 128 + (t16 & 7) * 16 + cl;  // gate-major output row
    int k = ch * 32 + q * 8 + j;
    float v = 0.f;
    if (k < 128) v = W_hh[row * 128 + k];
    else if (k < 144) v = W_ih[row * 16 + (k - 128)];
    Wg[n] = (_Float16)v;
    return;
  }
  n -= 81920;
  if (n < 98304) {
    int m = n >> 14, r = n & 16383;
    int ct = r >> 11, ch = (r >> 9) & 3, l = (r >> 3) & 63, j = r & 7;
    int q = l >> 4, cl = l & 15;
    int outcol = ct * 16 + cl, k = ch * 32 + q * 8 + j;
    W1p[n] = (_Float16)mW1[(m * 128 + k) * 128 + outcol];
    return;
  }
  n -= 98304;
  if (n < 98304) {
    int m = n >> 14, r = n & 16383;
    int ct = r >> 11, ch = (r >> 9) & 3, l = (r >> 3) & 63, j = r & 7;
    int q = l >> 4, cl = l & 15;
    int outcol = ct * 16 + cl, k = ch * 32 + q * 8 + j;
    W2p[n] = (_Float16)mW2[(m * 128 + k) * 128 + outcol];
    return;
  }
  n -= 98304;
  if (n < 16384) {
    int ct = n >> 11, ch = (n >> 9) & 3, l = (n >> 3) & 63, j = n & 7;
    int q = l >> 4, cl = l & 15;
    int outcol = ct * 16 + cl, k = ch * 32 + q * 8 + j;
    cW1p[n] = (_Float16)cW1[k * 128 + outcol];
    return;
  }
  n -= 16384;
  if (n < 16384) {
    int ct = n >> 11, ch = (n >> 9) & 3, l = (n >> 3) & 63, j = n & 7;
    int q = l >> 4, cl = l & 15;
    int outcol = ct * 16 + cl, k = ch * 32 + q * 8 + j;
    cW2p[n] = (_Float16)cW2[k * 128 + outcol];
    return;
  }
  n -= 16384;
  if (n < 512) bg[n] = b_ih[n] + b_hh[n];
}

// ---- main decoder: 1 wave per block, 32 rows per block, all 30 steps ----
__global__ __launch_bounds__(64, 1) void mmdec_main(
    const float* __restrict__ last_obs_rel, const float* __restrict__ h0, const float* __restrict__ c0,
    const float* __restrict__ W_se, const float* __restrict__ b_se,
    const float* __restrict__ mg1w, const float* __restrict__ mg1b,
    const float* __restrict__ mg2w, const float* __restrict__ mg2b,
    const float* __restrict__ mWo, const float* __restrict__ mbo,
    const float* __restrict__ cg1w, const float* __restrict__ cg1b,
    const float* __restrict__ cg2w, const float* __restrict__ cg2b,
    const float* __restrict__ cWo, const float* __restrict__ cbo,
    const _Float16* __restrict__ Wg, const _Float16* __restrict__ W1p, const _Float16* __restrict__ W2p,
    const _Float16* __restrict__ cW1p, const _Float16* __restrict__ cW2p, const float* __restrict__ bg,
    float* __restrict__ out) {
  // per-row LDS: h rows are [128 h | 16 x | 16 zeros] f16, stride 336 B
  __shared__ __align__(16) unsigned char h_smem[32 * 336];
  __shared__ __align__(16) unsigned char t1_smem[32 * 272];
  __shared__ __align__(16) float rel_smem[32 * 16];

  const int lane = threadIdx.x;
  const int q = lane >> 4;    // quad: k-offset for A frags, row-group for C
  const int cl = lane & 15;   // col within tile (C), row within tile (A)
  const int rowbase = blockIdx.x * 32;

  auto hrow = [&](int r) -> _Float16* { return (_Float16*)(h_smem + r * 336); };
  auto t1row = [&](int r) -> _Float16* { return (_Float16*)(t1_smem + r * 272); };

  // ---- init: h0 -> LDS (f16) ----
  {
    const int rr = lane & 31, half = lane >> 5;
    const float* src = h0 + (size_t)(rowbase + rr) * HD + half * 64;
    _Float16* dst = hrow(rr) + half * 64;
#pragma unroll
    for (int i = 0; i < 64; i += 8) {
      f16x8 v;
#pragma unroll
      for (int k = 0; k < 8; ++k) v[k] = (_Float16)src[i + k];
      *(f16x8*)(dst + i) = v;
    }
  }
  // ---- init: dec_in = selu(tile(last_obs_rel,6) @ W_se.T + b_se) -> x-cols; zero pad ----
  {
    const int rr = lane >> 1, e0 = (lane & 1) * 8;
    const float r0 = last_obs_rel[(size_t)(rowbase + rr) * 2 + 0];
    const float r1 = last_obs_rel[(size_t)(rowbase + rr) * 2 + 1];
    f16x8 v;
#pragma unroll
    for (int i = 0; i < 8; ++i) {
      const int e = e0 + i;
      float acc = b_se[e];
#pragma unroll
      for (int j = 0; j < 12; ++j) acc += ((j & 1) ? r1 : r0) * W_se[e * 12 + j];
      v[i] = (_Float16)selu_(acc);
    }
    *(f16x8*)(hrow(rr) + 128 + e0) = v;
    if (lane < 32) {
      f16x8 z;
#pragma unroll
      for (int i = 0; i < 8; ++i) z[i] = (_Float16)0.f;
      *(f16x8*)(hrow(lane) + 144) = z;
      *(f16x8*)(hrow(lane) + 152) = z;
    }
  }
  // ---- init: c0 -> fp32 registers in MFMA C-layout ----
  f32x4 cacc[2][8];
#pragma unroll
  for (int rt = 0; rt < 2; ++rt)
#pragma unroll
    for (int ct = 0; ct < 8; ++ct)
#pragma unroll
      for (int r = 0; r < 4; ++r)
        cacc[rt][ct][r] = c0[(size_t)(rowbase + rt * 16 + q * 4 + r) * HD + ct * 16 + cl];

  f32x4 hC[2][8];   // new h in C-layout (fp32) for residual adds
  f16x8 ah[2][4];   // A-frags of current h (K=128), reused by all 6 modes (+conf)
  __syncthreads();

  const size_t confbase = (size_t)B_ROWS * MM * TT * 2;

  for (int t = 0; t < TT; ++t) {
    // ======== LSTM gates: [h|x|0](K=160) @ Wg^T -> i,f,g,o; update c,h ========
    f16x8 afr[2][5];
#pragma unroll
    for (int rt = 0; rt < 2; ++rt)
#pragma unroll
      for (int ch = 0; ch < 5; ++ch)
        afr[rt][ch] = *(const f16x8*)(hrow(rt * 16 + cl) + ch * 32 + q * 8);

#pragma unroll
    for (int cg = 0; cg < 8; ++cg) {  // 16-channel group; gates i/f/g/o same channels
      f32x4 gacc[4][2];
#pragma unroll
      for (int g = 0; g < 4; ++g) {
        const _Float16* bp = Wg + (size_t)(g * 8 + cg) * 2560 + lane * 8;
        f32x4 a0 = {0.f, 0.f, 0.f, 0.f};
        f32x4 a1 = {0.f, 0.f, 0.f, 0.f};
#pragma unroll
        for (int ch = 0; ch < 5; ++ch) {
          f16x8 bfr = *(const f16x8*)(bp + ch * 512);
          a0 = __builtin_amdgcn_mfma_f32_16x16x32_f16(afr[0][ch], bfr, a0, 0, 0, 0);
          a1 = __builtin_amdgcn_mfma_f32_16x16x32_f16(afr[1][ch], bfr, a1, 0, 0, 0);
        }
        gacc[g][0] = a0;
        gacc[g][1] = a1;
      }
      const float bi = bg[cg * 16 + cl];
      const float bf_ = bg[128 + cg * 16 + cl];
      const float bgg = bg[256 + cg * 16 + cl];
      const float bo = bg[384 + cg * 16 + cl];
#pragma unroll
      for (int rt = 0; rt < 2; ++rt) {
        f32x4 hv;
#pragma unroll
        for (int r = 0; r < 4; ++r) {
          const float iv = sigm(gacc[0][rt][r] + bi);
          const float fv = sigm(gacc[1][rt][r] + bf_);
          const float gv = tanhf_(gacc[2][rt][r] + bgg);
          const float ov = sigm(gacc[3][rt][r] + bo);
          const float cn = fv * cacc[rt][cg][r] + iv * gv;
          cacc[rt][cg][r] = cn;
          const float hn = ov * tanhf_(cn);
          hv[r] = hn;
          hrow(rt * 16 + q * 4 + r)[cg * 16 + cl] = (_Float16)hn;
        }
        hC[rt][cg] = hv;
      }
    }
    __syncthreads();

    // ======== 6 mode heads ========
#pragma unroll
    for (int rt = 0; rt < 2; ++rt)
#pragma unroll
      for (int ch = 0; ch < 4; ++ch)
        ah[rt][ch] = *(const f16x8*)(hrow(rt * 16 + cl) + ch * 32 + q * 8);

    for (int m = 0; m < MM; ++m) {
      f32x4 tac[8][2];
      gemm128(ah, W1p + (size_t)m * HD * HD, lane, tac);
      f32x4 mean[2], rstd[2];
      gnstats(tac, mean, rstd);
#pragma unroll
      for (int ct = 0; ct < 8; ++ct) {
        const float g1 = mg1w[m * HD + ct * 16 + cl];
        const float b1 = mg1b[m * HD + ct * 16 + cl];
#pragma unroll
        for (int rt = 0; rt < 2; ++rt)
#pragma unroll
          for (int r = 0; r < 4; ++r) {
            float v = (tac[ct][rt][r] - mean[rt][r]) * rstd[rt][r] * g1 + b1;
            v = fmaxf(v, 0.f);
            t1row(rt * 16 + q * 4 + r)[ct * 16 + cl] = (_Float16)v;
          }
      }
      __syncthreads();
      f16x8 at1[2][4];
#pragma unroll
      for (int rt = 0; rt < 2; ++rt)
#pragma unroll
        for (int ch = 0; ch < 4; ++ch)
          at1[rt][ch] = *(const f16x8*)(t1row(rt * 16 + cl) + ch * 32 + q * 8);
      f32x4 t2a[8][2];
      gemm128(at1, W2p + (size_t)m * HD * HD, lane, t2a);
      gnstats(t2a, mean, rstd);
      // t = relu(gn(t2) + h); out = t @ mWo[m] + mbo[m]
      float po[2][4][2];
#pragma unroll
      for (int rt = 0; rt < 2; ++rt)
#pragma unroll
        for (int r = 0; r < 4; ++r) { po[rt][r][0] = 0.f; po[rt][r][1] = 0.f; }
#pragma unroll
      for (int ct = 0; ct < 8; ++ct) {
        const float g2 = mg2w[m * HD + ct * 16 + cl];
        const float b2 = mg2b[m * HD + ct * 16 + cl];
        const float w0 = mWo[((size_t)m * HD + ct * 16 + cl) * 2 + 0];
        const float w1 = mWo[((size_t)m * HD + ct * 16 + cl) * 2 + 1];
#pragma unroll
        for (int rt = 0; rt < 2; ++rt)
#pragma unroll
          for (int r = 0; r < 4; ++r) {
            float v = (t2a[ct][rt][r] - mean[rt][r]) * rstd[rt][r] * g2 + b2 + hC[rt][ct][r];
            v = fmaxf(v, 0.f);
            po[rt][r][0] += v * w0;
            po[rt][r][1] += v * w1;
          }
      }
#pragma unroll
      for (int sh = 1; sh < 16; sh <<= 1)
#pragma unroll
        for (int rt = 0; rt < 2; ++rt)
#pragma unroll
          for (int r = 0; r < 4; ++r) {
            po[rt][r][0] += __shfl_xor(po[rt][r][0], sh, 64);
            po[rt][r][1] += __shfl_xor(po[rt][r][1], sh, 64);
          }
      if (cl < 2) {
#pragma unroll
        for (int rt = 0; rt < 2; ++rt)
#pragma unroll
          for (int r = 0; r < 4; ++r) {
            const int rl_ = rt * 16 + q * 4 + r;
            const float val = (cl ? po[rt][r][1] : po[rt][r][0]) + mbo[m * 2 + cl];
            out[(((size_t)(rowbase + rl_) * MM + m) * TT + t) * 2 + cl] = val;
            rel_smem[rl_ * 16 + m * 2 + cl] = val;
          }
      }
    }
    __syncthreads();

    // ======== xin = selu(rel @ W_se.T + b_se) -> LDS x-cols ========
    {
      const int rr = lane >> 1, e0 = (lane & 1) * 8;
      float rl[12];
#pragma unroll
      for (int j = 0; j < 12; ++j) rl[j] = rel_smem[rr * 16 + j];
      f16x8 v;
#pragma unroll
      for (int i = 0; i < 8; ++i) {
        const int e = e0 + i;
        float acc = b_se[e];
#pragma unroll
        for (int j = 0; j < 12; ++j) acc += rl[j] * W_se[e * 12 + j];
        v[i] = (_Float16)selu_(acc);
      }
      *(f16x8*)(hrow(rr) + 128 + e0) = v;
    }
    __syncthreads();
  }

  // ======== confidence head on hT ========
  {
    f32x4 tac[8][2];
    gemm128(ah, cW1p, lane, tac);  // ah still holds hT A-frags
    f32x4 mean[2], rstd[2];
    gnstats(tac, mean, rstd);
#pragma unroll
    for (int ct = 0; ct < 8; ++ct) {
      const float g1 = cg1w[ct * 16 + cl];
      const float b1 = cg1b[ct * 16 + cl];
#pragma unroll
      for (int rt = 0; rt < 2; ++rt)
#pragma unroll
        for (int r = 0; r < 4; ++r) {
          float v = (tac[ct][rt][r] - mean[rt][r]) * rstd[rt][r] * g1 + b1;
          v = fmaxf(v, 0.f);
          t1row(rt * 16 + q * 4 + r)[ct * 16 + cl] = (_Float16)v;
        }
    }
    __syncthreads();
    f16x8 at1[2][4];
#pragma unroll
    for (int rt = 0; rt < 2; ++rt)
#pragma unroll
      for (int ch = 0; ch < 4; ++ch)
        at1[rt][ch] = *(const f16x8*)(t1row(rt * 16 + cl) + ch * 32 + q * 8);
    f32x4 t2a[8][2];
    gemm128(at1, cW2p, lane, t2a);
    gnstats(t2a, mean, rstd);

    float pl[2][4][6];
#pragma unroll
    for (int rt = 0; rt < 2; ++rt)
#pragma unroll
      for (int r = 0; r < 4; ++r)
#pragma unroll
        for (int k = 0; k < 6; ++k) pl[rt][r][k] = 0.f;
#pragma unroll
    for (int ct = 0; ct < 8; ++ct) {
      const float g2 = cg2w[ct * 16 + cl];
      const float b2 = cg2b[ct * 16 + cl];
      float wo[6];
#pragma unroll
      for (int k = 0; k < 6; ++k) wo[k] = cWo[(ct * 16 + cl) * 6 + k];
#pragma unroll
      for (int rt = 0; rt < 2; ++rt)
#pragma unroll
        for (int r = 0; r < 4; ++r) {
          float v = (t2a[ct][rt][r] - mean[rt][r]) * rstd[rt][r] * g2 + b2 + hC[rt][ct][r];
          v = fmaxf(v, 0.f);
#pragma unroll
          for (int k = 0; k < 6; ++k) pl[rt][r][k] += v * wo[k];
        }
    }
#pragma unroll
    for (int sh = 1; sh < 16; sh <<= 1)
#pragma unroll
      for (int rt = 0; rt < 2; ++rt)
#pragma unroll
        for (int r = 0; r < 4; ++r)
#pragma unroll
          for (int k = 0; k < 6; ++k) pl[rt][r][k] += __shfl_xor(pl[rt][r][k], sh, 64);
    if (cl == 0) {
#pragma unroll
      for (int rt = 0; rt < 2; ++rt)
#pragma unroll
        for (int r = 0; r < 4; ++r) {
          float l[6];
#pragma unroll
          for (int k = 0; k < 6; ++k) l[k] = pl[rt][r][k] + cbo[k];
          float mx = l[0];
#pragma unroll
          for (int k = 1; k < 6; ++k) mx = fmaxf(mx, l[k]);
          float s = 0.f;
#pragma unroll
          for (int k = 0; k < 6; ++k) { l[k] = __expf(l[k] - mx); s += l[k]; }
          const float inv = fast_rcp(s);
          const size_t row = rowbase + rt * 16 + q * 4 + r;
#pragma unroll
          for (int k = 0; k < 6; ++k) out[confbase + row * 6 + k] = l[k] * inv;
        }
    }
  }
}

extern "C" void kernel_launch(void* const* d_in, const int* in_sizes, int n_in,
                              void* d_out, int out_size, void* d_ws, size_t ws_size,
                              hipStream_t stream) {
  (void)in_sizes; (void)n_in; (void)out_size; (void)ws_size;
  const float* last_obs_rel = (const float*)d_in[1];
  const float* h0   = (const float*)d_in[2];
  const float* c0   = (const float*)d_in[3];
  const float* W_se = (const float*)d_in[4];
  const float* b_se = (const float*)d_in[5];
  const float* W_ih = (const float*)d_in[6];
  const float* W_hh = (const float*)d_in[7];
  const float* b_ih = (const float*)d_in[8];
  const float* b_hh = (const float*)d_in[9];
  const float* mW1  = (const float*)d_in[10];
  const float* mg1w = (const float*)d_in[11];
  const float* mg1b = (const float*)d_in[12];
  const float* mW2  = (const float*)d_in[13];
  const float* mg2w = (const float*)d_in[14];
  const float* mg2b = (const float*)d_in[15];
  const float* mWo  = (const float*)d_in[16];
  const float* mbo  = (const float*)d_in[17];
  const float* cW1  = (const float*)d_in[18];
  const float* cg1w = (const float*)d_in[19];
  const float* cg1b = (const float*)d_in[20];
  const float* cW2  = (const float*)d_in[21];
  const float* cg2w = (const float*)d_in[22];
  const float* cg2b = (const float*)d_in[23];
  const float* cWo  = (const float*)d_in[24];
  const float* cbo  = (const float*)d_in[25];

  char* ws = (char*)d_ws;
  _Float16* Wg   = (_Float16*)(ws + 0);       // 512*160 f16   = 163840 B
  _Float16* W1p  = (_Float16*)(ws + 163840);  // 6*128*128 f16 = 196608 B
  _Float16* W2p  = (_Float16*)(ws + 360448);  // 6*128*128 f16 = 196608 B
  _Float16* cW1p = (_Float16*)(ws + 557056);  // 128*128 f16   =  32768 B
  _Float16* cW2p = (_Float16*)(ws + 589824);  // 128*128 f16   =  32768 B
  float*    bg   = (float*)   (ws + 622592);  // 512 f32       =   2048 B

  prep_weights<<<1218, 256, 0, stream>>>(W_ih, W_hh, b_ih, b_hh, mW1, mW2, cW1, cW2,
                                         Wg, W1p, W2p, cW1p, cW2p, bg);
  mmdec_main<<<1024, 64, 0, stream>>>(last_obs_rel, h0, c0, W_se, b_se,
                                      mg1w, mg1b, mg2w, mg2b, mWo, mbo,
                                      cg1w, cg1b, cg2w, cg2b, cWo, cbo,
                                      Wg, W1p, W2p, cW1p, cW2p, bg, (float*)d_out);
}